// Round 2
// baseline (677.814 us; speedup 1.0000x reference)
//
#include <hip/hip_runtime.h>
#include <hip/hip_bf16.h>
#include <stdint.h>

#define DIM 3072
#define SEQ 4096
#define NH 24
#define HD 128

typedef __hip_bfloat16 bf16;
typedef __bf16 bfv8 __attribute__((ext_vector_type(8)));
typedef float f32x4 __attribute__((ext_vector_type(4)));
typedef unsigned short us4 __attribute__((ext_vector_type(4)));
typedef unsigned short us8 __attribute__((ext_vector_type(8)));
typedef unsigned int u32x2 __attribute__((ext_vector_type(2)));

__device__ __forceinline__ void async16(void* lds, const void* g) {
  __builtin_amdgcn_global_load_lds((const __attribute__((address_space(1))) void*)g,
                                   (__attribute__((address_space(3))) void*)lds, 16, 0, 0);
}

__device__ __forceinline__ unsigned short f2bf(float f) {
  unsigned int u = __builtin_bit_cast(unsigned int, f);
  u += 0x7fffu + ((u >> 16) & 1u);
  return (unsigned short)(u >> 16);
}
__device__ __forceinline__ float bf2f(unsigned short b) {
  return __builtin_bit_cast(float, (unsigned int)b << 16);
}

#define MFMA16(a, b, c) __builtin_amdgcn_mfma_f32_16x16x32_bf16((a), (b), (c), 0, 0, 0)

// ---------------- kernel 1: fp32 -> bf16 cast (hidden states) ----------------
__global__ __launch_bounds__(256) void k_cast(const float4* __restrict__ in,
                                              us4* __restrict__ o, int n4) {
  int i = blockIdx.x * 256 + threadIdx.x;
  if (i >= n4) return;
  float4 v = in[i];
  us4 r;
  r.x = f2bf(v.x); r.y = f2bf(v.y); r.z = f2bf(v.z); r.w = f2bf(v.w);
  o[i] = r;
}

// ------------- kernel 2: transpose-cast W (KxN fp32) -> WT (NxK bf16) -------------
__global__ __launch_bounds__(256) void k_transW(const float* __restrict__ W0,
    const float* __restrict__ W1, const float* __restrict__ W2,
    unsigned short* __restrict__ T0, unsigned short* __restrict__ T1,
    unsigned short* __restrict__ T2) {
  int z = blockIdx.z;
  const float* W = (z == 0) ? W0 : (z == 1) ? W1 : W2;
  unsigned short* T = (z == 0) ? T0 : (z == 1) ? T1 : T2;
  int kb = blockIdx.y * 64;
  int nb = blockIdx.x * 64;
  __shared__ float tile[64 * 64];
  int t = threadIdx.x;
#pragma unroll
  for (int p = 0; p < 4; ++p) {
    int cid = p * 256 + t;
    int row = cid >> 4, c4 = cid & 15;           // row = k-local
    int slot = (c4 + (row >> 3)) & 15;           // rotate slots by k>>3
    float4 v = *(const float4*)&W[(size_t)(kb + row) * DIM + nb + c4 * 4];
    *(float4*)&tile[row * 64 + slot * 4] = v;
  }
  __syncthreads();
  // output phase: 64 n-rows x 8 k-chunks = 512 work-items (exact cover; was
  // p<4 == 1024 which raced into the next block's rows and wrote OOB)
#pragma unroll
  for (int p = 0; p < 2; ++p) {
    int cid = p * 256 + t;
    int nl = cid >> 3, c8 = cid & 7;             // nl = n-local
    us8 o;
#pragma unroll
    for (int j = 0; j < 8; ++j) {
      int k = c8 * 8 + j;
      int slot = ((nl >> 2) + (k >> 3)) & 15;
      o[j] = f2bf(tile[k * 64 + slot * 4 + (nl & 3)]);
    }
    *(us8*)&T[(size_t)(nb + nl) * DIM + kb + c8 * 8] = o;
  }
}

// ------------- kernel 3: GEMM  out[s][n] = hs[s][:] . WT[n][:] + bias[n] -------------
// 128x128 tile, BK=64, 4 waves, 16x16x32 bf16 MFMA, global_load_lds w/ source-side swizzle.
// Output written head-major bf16: out[h][s][d].
__global__ __launch_bounds__(256, 2) void k_gemm(const unsigned short* __restrict__ A,
    const unsigned short* __restrict__ B0, const unsigned short* __restrict__ B1,
    const unsigned short* __restrict__ B2, const float* __restrict__ c0,
    const float* __restrict__ c1, const float* __restrict__ c2,
    unsigned short* __restrict__ o0, unsigned short* __restrict__ o1,
    unsigned short* __restrict__ o2) {
  const int z = blockIdx.z;
  const unsigned short* Bt = (z == 0) ? B0 : (z == 1) ? B1 : B2;
  const float* bias = (z == 0) ? c0 : (z == 1) ? c1 : c2;
  unsigned short* outp = (z == 0) ? o0 : (z == 1) ? o1 : o2;
  const int nb = blockIdx.x * 128;
  const int mb = blockIdx.y * 128;
  const int t = threadIdx.x;
  const int w = t >> 6, l = t & 63;
  const int wr = w >> 1, wc = w & 1;
  const int lq = l & 15, lg = l >> 4;
  __shared__ unsigned short lA[128 * 64];
  __shared__ unsigned short lB[128 * 64];
  f32x4 acc[4][4];
#pragma unroll
  for (int i = 0; i < 4; ++i)
#pragma unroll
    for (int j = 0; j < 4; ++j) acc[i][j] = (f32x4){0.f, 0.f, 0.f, 0.f};

  for (int kb = 0; kb < DIM; kb += 64) {
    __syncthreads();
#pragma unroll
    for (int r = 0; r < 4; ++r) {
      int row = (w * 4 + r) * 8 + (l >> 3);
      int sl = (l & 7) ^ (row & 7);              // pre-swizzled global source slot
      async16(&lA[(w * 4 + r) * 512], A + (size_t)(mb + row) * DIM + kb + sl * 8);
      async16(&lB[(w * 4 + r) * 512], Bt + (size_t)(nb + row) * DIM + kb + sl * 8);
    }
    __syncthreads();
#pragma unroll
    for (int kc = 0; kc < 2; ++kc) {
      bfv8 af[4], bfv[4];
#pragma unroll
      for (int mf = 0; mf < 4; ++mf) {
        int row = wr * 64 + mf * 16 + lq;
        af[mf] = *(const bfv8*)&lA[row * 64 + (((kc * 4 + lg) ^ (row & 7)) * 8)];
      }
#pragma unroll
      for (int nf = 0; nf < 4; ++nf) {
        int row = wc * 64 + nf * 16 + lq;
        bfv[nf] = *(const bfv8*)&lB[row * 64 + (((kc * 4 + lg) ^ (row & 7)) * 8)];
      }
#pragma unroll
      for (int mf = 0; mf < 4; ++mf)
#pragma unroll
        for (int nf = 0; nf < 4; ++nf)
          acc[mf][nf] = MFMA16(af[mf], bfv[nf], acc[mf][nf]);
    }
  }
  // epilogue: + bias, write bf16 head-major
#pragma unroll
  for (int nf = 0; nf < 4; ++nf) {
    int n = nb + wc * 64 + nf * 16 + lq;
    float bv_ = bias[n];
    int hh = n >> 7, dd = n & 127;
    unsigned short* obase = outp + (size_t)hh * SEQ * HD + dd;
#pragma unroll
    for (int mf = 0; mf < 4; ++mf) {
      int srow = mb + wr * 64 + mf * 16 + lg * 4;
#pragma unroll
      for (int r = 0; r < 4; ++r)
        obase[(size_t)(srow + r) * HD] = f2bf(acc[mf][nf][r] + bv_);
    }
  }
}

// ------------- kernel 4: per-(h,s)-row RMSNorm + RoPE (in place, bf16) -------------
// one wave per row; q additionally scaled by 1/sqrt(HD)
__global__ __launch_bounds__(256) void k_rmsrope(unsigned short* __restrict__ qb,
    unsigned short* __restrict__ kbuf, const float* __restrict__ cosT,
    const float* __restrict__ sinT, const float* __restrict__ gq,
    const float* __restrict__ gk) {
  int rowid = blockIdx.x * 4 + (threadIdx.x >> 6);
  int l = threadIdx.x & 63;
  int which = (rowid >= NH * SEQ) ? 1 : 0;
  int r2 = which ? rowid - NH * SEQ : rowid;
  int hh = r2 >> 12;
  int s = r2 & 4095;
  unsigned short* base = (which ? kbuf : qb) + ((size_t)hh * SEQ + s) * HD + 2 * l;
  const float* g = which ? gk : gq;
  unsigned int u = *(const unsigned int*)base;
  float x0 = bf2f((unsigned short)(u & 0xffffu));
  float x1 = bf2f((unsigned short)(u >> 16));
  float ss = x0 * x0 + x1 * x1;
#pragma unroll
  for (int o = 1; o < 64; o <<= 1) ss += __shfl_xor(ss, o);
  float rr = rsqrtf(ss * (1.0f / 128.0f) + 1e-6f);
  int d0 = 2 * l;
  float c0v = cosT[s * HD + d0], c1v = cosT[s * HD + d0 + 1];
  float s0v = sinT[s * HD + d0], s1v = sinT[s * HD + d0 + 1];
  float y0 = x0 * rr * g[d0];
  float y1 = x1 * rr * g[d0 + 1];
  float o0 = y0 * c0v - y1 * s0v;
  float o1 = y1 * c1v + y0 * s1v;
  if (!which) { o0 *= 0.08838834764831845f; o1 *= 0.08838834764831845f; }
  *(unsigned int*)base = (unsigned int)f2bf(o0) | ((unsigned int)f2bf(o1) << 16);
}

// ------------- kernel 5: V transpose  v[h][s][d] -> vt[h][d][s] -------------
__global__ __launch_bounds__(256) void k_transV(const unsigned short* __restrict__ vb,
                                                unsigned short* __restrict__ vt) {
  int hh = blockIdx.y;
  int sb = blockIdx.x * 64;
  __shared__ unsigned short tile[64 * 128];
  int t = threadIdx.x;
#pragma unroll
  for (int p = 0; p < 4; ++p) {
    int cid = p * 256 + t;
    int row = cid >> 4, c = cid & 15;            // row = s-local
    int slot = (c + (row >> 3)) & 15;            // rotate by s>>3
    us8 v = *(const us8*)&vb[((size_t)hh * SEQ + sb + row) * HD + c * 8];
    *(us8*)&tile[row * 128 + slot * 8] = v;
  }
  __syncthreads();
#pragma unroll
  for (int p = 0; p < 4; ++p) {
    int cid = p * 256 + t;
    int d = cid >> 3, c8 = cid & 7;
    us8 o;
#pragma unroll
    for (int j = 0; j < 8; ++j) {
      int s = c8 * 8 + j;
      int slot = ((d >> 3) + (s >> 3)) & 15;
      o[j] = tile[s * 128 + slot * 8 + (d & 7)];
    }
    *(us8*)&vt[((size_t)hh * HD + d) * SEQ + sb + c8 * 8] = o;
  }
}

// ------------- kernel 6: flash attention -------------
// grid (SEQ/64, NH); 4 waves, each owns 16 q rows. KV tile = 64.
// swapped QK^T: S^T = mfma(K, Q) so the softmax row (kv axis) is lane-local-ish.
__global__ __launch_bounds__(256, 2) void k_attn(const unsigned short* __restrict__ qg,
    const unsigned short* __restrict__ kg, const unsigned short* __restrict__ vtg,
    float* __restrict__ outp) {
  const int h = blockIdx.y;
  const int qb0 = blockIdx.x * 64;
  const int t = threadIdx.x;
  const int w = t >> 6, l = t & 63;
  const int lq = l & 15, lg = l >> 4;

  __shared__ unsigned short lK[64 * 128];   // [kv][d], XOR-swizzled
  __shared__ unsigned short lV[128 * 64];   // [d][kv], XOR-swizzled
  __shared__ unsigned short lP[4][16 * 64]; // per-wave P [q][kv], XOR-swizzled

  bfv8 qf[4];
  {
    const unsigned short* qrow = qg + ((size_t)h * SEQ + qb0 + w * 16 + lq) * HD;
#pragma unroll
    for (int c = 0; c < 4; ++c) qf[c] = *(const bfv8*)(qrow + c * 32 + lg * 8);
  }

  f32x4 oacc[8];
#pragma unroll
  for (int i = 0; i < 8; ++i) oacc[i] = (f32x4){0.f, 0.f, 0.f, 0.f};
  float m_run = -3.0e38f, l_run = 0.f;

  for (int kb = 0; kb < SEQ; kb += 64) {
    __syncthreads();
#pragma unroll
    for (int r = 0; r < 4; ++r) {                 // K tile: rows 256B, 16 slots
      int row = (w * 4 + r) * 4 + lg;
      int sl = lq ^ (row & 7);
      async16(&lK[(w * 4 + r) * 512], kg + ((size_t)h * SEQ + kb + row) * HD + sl * 8);
    }
#pragma unroll
    for (int r = 0; r < 4; ++r) {                 // V^T tile: rows 128B, 8 slots
      int row = (w * 4 + r) * 8 + (l >> 3);
      int sl = (l & 7) ^ (row & 7);
      async16(&lV[(w * 4 + r) * 512], vtg + ((size_t)h * HD + row) * SEQ + kb + sl * 8);
    }
    __syncthreads();

    // S^T = K . Q^T   (4 kv-frags of 16)
    f32x4 st[4];
#pragma unroll
    for (int i = 0; i < 4; ++i) st[i] = (f32x4){0.f, 0.f, 0.f, 0.f};
#pragma unroll
    for (int kvf = 0; kvf < 4; ++kvf) {
      int row = kvf * 16 + lq;
      int swz = row & 7;
#pragma unroll
      for (int kc = 0; kc < 4; ++kc) {
        bfv8 kf = *(const bfv8*)&lK[row * 128 + (((kc * 4 + lg) ^ swz) * 8)];
        st[kvf] = MFMA16(kf, qf[kc], st[kvf]);
      }
    }
    // online softmax; lane holds 16 scores for q = lq (kv = kvf*16 + lg*4 + r)
    float tmax = st[0][0];
#pragma unroll
    for (int f2 = 0; f2 < 4; ++f2)
#pragma unroll
      for (int r2 = 0; r2 < 4; ++r2) tmax = fmaxf(tmax, st[f2][r2]);
    tmax = fmaxf(tmax, __shfl_xor(tmax, 16));
    tmax = fmaxf(tmax, __shfl_xor(tmax, 32));
    float m_new = fmaxf(m_run, tmax);
    float p[4][4];
    float lsum = 0.f;
#pragma unroll
    for (int f2 = 0; f2 < 4; ++f2)
#pragma unroll
      for (int r2 = 0; r2 < 4; ++r2) {
        float e = __expf(st[f2][r2] - m_new);
        p[f2][r2] = e;
        lsum += e;
      }
    lsum += __shfl_xor(lsum, 16);
    lsum += __shfl_xor(lsum, 32);
    float alpha = __expf(m_run - m_new);
    m_run = m_new;
    l_run = l_run * alpha + lsum;

    // write P (bf16) to per-wave LDS in [q][kv] with same XOR swizzle
    unsigned short* pw = &lP[w][0];
#pragma unroll
    for (int f2 = 0; f2 < 4; ++f2) {
      u32x2 pv;
      pv.x = (unsigned int)f2bf(p[f2][0]) | ((unsigned int)f2bf(p[f2][1]) << 16);
      pv.y = (unsigned int)f2bf(p[f2][2]) | ((unsigned int)f2bf(p[f2][3]) << 16);
      int eo = lq * 64 + (((f2 * 2 + (lg >> 1)) ^ (lq & 7)) * 8) + (lg & 1) * 4;
      *(u32x2*)&pw[eo] = pv;
    }
    asm volatile("" ::: "memory");  // order P writes before P reads (same wave)

    // rescale O accumulator: O rows are q = lg*4 + r
    float ar[4];
#pragma unroll
    for (int r2 = 0; r2 < 4; ++r2) ar[r2] = __shfl(alpha, lg * 4 + r2);
#pragma unroll
    for (int df = 0; df < 8; ++df)
#pragma unroll
      for (int r2 = 0; r2 < 4; ++r2) oacc[df][r2] *= ar[r2];

    // O += P . V
#pragma unroll
    for (int m = 0; m < 2; ++m) {
      bfv8 pa = *(const bfv8*)&pw[lq * 64 + (((m * 4 + lg) ^ (lq & 7)) * 8)];
#pragma unroll
      for (int df = 0; df < 8; ++df) {
        int vrow = df * 16 + lq;
        bfv8 vf = *(const bfv8*)&lV[vrow * 64 + (((m * 4 + lg) ^ (vrow & 7)) * 8)];
        oacc[df] = MFMA16(pa, vf, oacc[df]);
      }
    }
  }
  // epilogue: divide by l, write fp32 out[s][h*128+d] (coalesced 64B per 16-lane group)
  float li[4];
#pragma unroll
  for (int r2 = 0; r2 < 4; ++r2) li[r2] = 1.0f / __shfl(l_run, lg * 4 + r2);
#pragma unroll
  for (int df = 0; df < 8; ++df)
#pragma unroll
    for (int r2 = 0; r2 < 4; ++r2)
      outp[(size_t)(qb0 + w * 16 + lg * 4 + r2) * DIM + h * HD + df * 16 + lq] =
          oacc[df][r2] * li[r2];
}

extern "C" void kernel_launch(void* const* d_in, const int* in_sizes, int n_in,
                              void* d_out, int out_size, void* d_ws, size_t ws_size,
                              hipStream_t stream) {
  const float* hs = (const float*)d_in[0];
  const float* cosT = (const float*)d_in[1];
  const float* sinT = (const float*)d_in[2];
  const float* Wq = (const float*)d_in[3];
  const float* bq = (const float*)d_in[4];
  const float* Wk = (const float*)d_in[5];
  const float* bk = (const float*)d_in[6];
  const float* Wv = (const float*)d_in[7];
  const float* bv = (const float*)d_in[8];
  const float* gq = (const float*)d_in[9];
  const float* gk = (const float*)d_in[10];
  float* out = (float*)d_out;

  char* ws = (char*)d_ws;
  const size_t SZ_HS = (size_t)SEQ * DIM * 2;       // 25165824
  const size_t SZ_W = (size_t)DIM * DIM * 2;        // 18874368
  const size_t SZ_HEAD = (size_t)NH * SEQ * HD * 2; // 25165824
  unsigned short* hsb = (unsigned short*)ws;               ws += SZ_HS;
  unsigned short* WqT = (unsigned short*)ws;               ws += SZ_W;
  unsigned short* WkT = (unsigned short*)ws;               ws += SZ_W;
  unsigned short* WvT = (unsigned short*)ws;               ws += SZ_W;
  unsigned short* q_b = (unsigned short*)ws;               ws += SZ_HEAD;
  unsigned short* k_b = (unsigned short*)ws;               ws += SZ_HEAD;
  unsigned short* v_b = (unsigned short*)ws;               ws += SZ_HEAD;
  unsigned short* vtr = (unsigned short*)ws;               ws += SZ_HEAD;

  int n4 = SEQ * DIM / 4;
  k_cast<<<dim3(n4 / 256), dim3(256), 0, stream>>>((const float4*)hs, (us4*)hsb, n4);
  k_transW<<<dim3(48, 48, 3), dim3(256), 0, stream>>>(Wq, Wk, Wv, WqT, WkT, WvT);
  k_gemm<<<dim3(24, 32, 3), dim3(256), 0, stream>>>(hsb, WqT, WkT, WvT, bq, bk, bv,
                                                    q_b, k_b, v_b);
  k_rmsrope<<<dim3(2 * NH * SEQ / 4), dim3(256), 0, stream>>>(q_b, k_b, cosT, sinT, gq, gk);
  k_transV<<<dim3(64, 24), dim3(256), 0, stream>>>(v_b, vtr);
  k_attn<<<dim3(64, 24), dim3(256), 0, stream>>>(q_b, k_b, vtr, out);
}

// Round 3
// 623.455 us; speedup vs baseline: 1.0872x; 1.0872x over previous
//
#include <hip/hip_runtime.h>
#include <hip/hip_bf16.h>
#include <stdint.h>

#define DIM 3072
#define SEQ 4096
#define NH 24
#define HD 128

typedef __hip_bfloat16 bf16;
typedef __bf16 bfv8 __attribute__((ext_vector_type(8)));
typedef float f32x4 __attribute__((ext_vector_type(4)));
typedef float f32x16 __attribute__((ext_vector_type(16)));
typedef unsigned short us4 __attribute__((ext_vector_type(4)));
typedef unsigned short us8 __attribute__((ext_vector_type(8)));

__device__ __forceinline__ void async16(void* lds, const void* g) {
  __builtin_amdgcn_global_load_lds((const __attribute__((address_space(1))) void*)g,
                                   (__attribute__((address_space(3))) void*)lds, 16, 0, 0);
}

__device__ __forceinline__ unsigned short f2bf(float f) {
  unsigned int u = __builtin_bit_cast(unsigned int, f);
  u += 0x7fffu + ((u >> 16) & 1u);
  return (unsigned short)(u >> 16);
}
__device__ __forceinline__ float bf2f(unsigned short b) {
  return __builtin_bit_cast(float, (unsigned int)b << 16);
}
__device__ __forceinline__ unsigned int cvtpk(float lo, float hi) {
  unsigned int r;
  asm("v_cvt_pk_bf16_f32 %0, %1, %2" : "=v"(r) : "v"(lo), "v"(hi));
  return r;
}
__device__ __forceinline__ void pl32swap(unsigned int& a, unsigned int& b) {
  asm volatile("v_permlane32_swap_b32 %0, %1" : "+v"(a), "+v"(b));
}

#define MFMA16(a, b, c) __builtin_amdgcn_mfma_f32_16x16x32_bf16((a), (b), (c), 0, 0, 0)
#define MFMA32(a, b, c) __builtin_amdgcn_mfma_f32_32x32x16_bf16((a), (b), (c), 0, 0, 0)

// ---------------- kernel 1: fp32 -> bf16 cast (hidden states) ----------------
__global__ __launch_bounds__(256) void k_cast(const float4* __restrict__ in,
                                              us4* __restrict__ o, int n4) {
  int i = blockIdx.x * 256 + threadIdx.x;
  if (i >= n4) return;
  float4 v = in[i];
  us4 r;
  r.x = f2bf(v.x); r.y = f2bf(v.y); r.z = f2bf(v.z); r.w = f2bf(v.w);
  o[i] = r;
}

// ------------- kernel 2: transpose-cast W (KxN fp32) -> WT (NxK bf16) -------------
__global__ __launch_bounds__(256) void k_transW(const float* __restrict__ W0,
    const float* __restrict__ W1, const float* __restrict__ W2,
    unsigned short* __restrict__ T0, unsigned short* __restrict__ T1,
    unsigned short* __restrict__ T2) {
  int z = blockIdx.z;
  const float* W = (z == 0) ? W0 : (z == 1) ? W1 : W2;
  unsigned short* T = (z == 0) ? T0 : (z == 1) ? T1 : T2;
  int kb = blockIdx.y * 64;
  int nb = blockIdx.x * 64;
  __shared__ float tile[64 * 64];
  int t = threadIdx.x;
#pragma unroll
  for (int p = 0; p < 4; ++p) {
    int cid = p * 256 + t;
    int row = cid >> 4, c4 = cid & 15;           // row = k-local
    int slot = (c4 + (row >> 3)) & 15;           // rotate slots by k>>3
    float4 v = *(const float4*)&W[(size_t)(kb + row) * DIM + nb + c4 * 4];
    *(float4*)&tile[row * 64 + slot * 4] = v;
  }
  __syncthreads();
  // output phase: 64 n-rows x 8 k-chunks = 512 work-items (exact cover)
#pragma unroll
  for (int p = 0; p < 2; ++p) {
    int cid = p * 256 + t;
    int nl = cid >> 3, c8 = cid & 7;             // nl = n-local
    us8 o;
#pragma unroll
    for (int j = 0; j < 8; ++j) {
      int k = c8 * 8 + j;
      int slot = ((nl >> 2) + (k >> 3)) & 15;
      o[j] = f2bf(tile[k * 64 + slot * 4 + (nl & 3)]);
    }
    *(us8*)&T[(size_t)(nb + nl) * DIM + kb + c8 * 8] = o;
  }
}

// ------------- kernel 3: GEMM  out[s][n] = hs[s][:] . WT[n][:] + bias[n] -------------
__global__ __launch_bounds__(256, 2) void k_gemm(const unsigned short* __restrict__ A,
    const unsigned short* __restrict__ B0, const unsigned short* __restrict__ B1,
    const unsigned short* __restrict__ B2, const float* __restrict__ c0,
    const float* __restrict__ c1, const float* __restrict__ c2,
    unsigned short* __restrict__ o0, unsigned short* __restrict__ o1,
    unsigned short* __restrict__ o2) {
  const int z = blockIdx.z;
  const unsigned short* Bt = (z == 0) ? B0 : (z == 1) ? B1 : B2;
  const float* bias = (z == 0) ? c0 : (z == 1) ? c1 : c2;
  unsigned short* outp = (z == 0) ? o0 : (z == 1) ? o1 : o2;
  const int nb = blockIdx.x * 128;
  const int mb = blockIdx.y * 128;
  const int t = threadIdx.x;
  const int w = t >> 6, l = t & 63;
  const int wr = w >> 1, wc = w & 1;
  const int lq = l & 15, lg = l >> 4;
  __shared__ unsigned short lA[128 * 64];
  __shared__ unsigned short lB[128 * 64];
  f32x4 acc[4][4];
#pragma unroll
  for (int i = 0; i < 4; ++i)
#pragma unroll
    for (int j = 0; j < 4; ++j) acc[i][j] = (f32x4){0.f, 0.f, 0.f, 0.f};

  for (int kb = 0; kb < DIM; kb += 64) {
    __syncthreads();
#pragma unroll
    for (int r = 0; r < 4; ++r) {
      int row = (w * 4 + r) * 8 + (l >> 3);
      int sl = (l & 7) ^ (row & 7);              // pre-swizzled global source slot
      async16(&lA[(w * 4 + r) * 512], A + (size_t)(mb + row) * DIM + kb + sl * 8);
      async16(&lB[(w * 4 + r) * 512], Bt + (size_t)(nb + row) * DIM + kb + sl * 8);
    }
    __syncthreads();
#pragma unroll
    for (int kc = 0; kc < 2; ++kc) {
      bfv8 af[4], bfv[4];
#pragma unroll
      for (int mf = 0; mf < 4; ++mf) {
        int row = wr * 64 + mf * 16 + lq;
        af[mf] = *(const bfv8*)&lA[row * 64 + (((kc * 4 + lg) ^ (row & 7)) * 8)];
      }
#pragma unroll
      for (int nf = 0; nf < 4; ++nf) {
        int row = wc * 64 + nf * 16 + lq;
        bfv[nf] = *(const bfv8*)&lB[row * 64 + (((kc * 4 + lg) ^ (row & 7)) * 8)];
      }
#pragma unroll
      for (int mf = 0; mf < 4; ++mf)
#pragma unroll
        for (int nf = 0; nf < 4; ++nf)
          acc[mf][nf] = MFMA16(af[mf], bfv[nf], acc[mf][nf]);
    }
  }
#pragma unroll
  for (int nf = 0; nf < 4; ++nf) {
    int n = nb + wc * 64 + nf * 16 + lq;
    float bv_ = bias[n];
    int hh = n >> 7, dd = n & 127;
    unsigned short* obase = outp + (size_t)hh * SEQ * HD + dd;
#pragma unroll
    for (int mf = 0; mf < 4; ++mf) {
      int srow = mb + wr * 64 + mf * 16 + lg * 4;
#pragma unroll
      for (int r = 0; r < 4; ++r)
        obase[(size_t)(srow + r) * HD] = f2bf(acc[mf][nf][r] + bv_);
    }
  }
}

// ------------- kernel 4: per-(h,s)-row RMSNorm + RoPE (in place, bf16) -------------
// q additionally scaled by log2(e)/sqrt(HD) so attention works in exp2 domain
__global__ __launch_bounds__(256) void k_rmsrope(unsigned short* __restrict__ qb,
    unsigned short* __restrict__ kbuf, const float* __restrict__ cosT,
    const float* __restrict__ sinT, const float* __restrict__ gq,
    const float* __restrict__ gk) {
  int rowid = blockIdx.x * 4 + (threadIdx.x >> 6);
  int l = threadIdx.x & 63;
  int which = (rowid >= NH * SEQ) ? 1 : 0;
  int r2 = which ? rowid - NH * SEQ : rowid;
  int hh = r2 >> 12;
  int s = r2 & 4095;
  unsigned short* base = (which ? kbuf : qb) + ((size_t)hh * SEQ + s) * HD + 2 * l;
  const float* g = which ? gk : gq;
  unsigned int u = *(const unsigned int*)base;
  float x0 = bf2f((unsigned short)(u & 0xffffu));
  float x1 = bf2f((unsigned short)(u >> 16));
  float ss = x0 * x0 + x1 * x1;
#pragma unroll
  for (int o = 1; o < 64; o <<= 1) ss += __shfl_xor(ss, o);
  float rr = rsqrtf(ss * (1.0f / 128.0f) + 1e-6f);
  int d0 = 2 * l;
  float c0v = cosT[s * HD + d0], c1v = cosT[s * HD + d0 + 1];
  float s0v = sinT[s * HD + d0], s1v = sinT[s * HD + d0 + 1];
  float y0 = x0 * rr * g[d0];
  float y1 = x1 * rr * g[d0 + 1];
  float o0 = y0 * c0v - y1 * s0v;
  float o1 = y1 * c1v + y0 * s1v;
  if (!which) { o0 *= 0.1275174373f; o1 *= 0.1275174373f; } // log2(e)/sqrt(128)
  *(unsigned int*)base = (unsigned int)f2bf(o0) | ((unsigned int)f2bf(o1) << 16);
}

// ------------- kernel 5: V transpose  v[h][s][d] -> vt[h][d][s] -------------
__global__ __launch_bounds__(256) void k_transV(const unsigned short* __restrict__ vb,
                                                unsigned short* __restrict__ vt) {
  int hh = blockIdx.y;
  int sb = blockIdx.x * 64;
  __shared__ unsigned short tile[64 * 128];
  int t = threadIdx.x;
#pragma unroll
  for (int p = 0; p < 4; ++p) {
    int cid = p * 256 + t;
    int row = cid >> 4, c = cid & 15;            // row = s-local
    int slot = (c + (row >> 3)) & 15;            // rotate by s>>3
    us8 v = *(const us8*)&vb[((size_t)hh * SEQ + sb + row) * HD + c * 8];
    *(us8*)&tile[row * 128 + slot * 8] = v;
  }
  __syncthreads();
#pragma unroll
  for (int p = 0; p < 4; ++p) {
    int cid = p * 256 + t;
    int d = cid >> 3, c8 = cid & 7;
    us8 o;
#pragma unroll
    for (int j = 0; j < 8; ++j) {
      int s = c8 * 8 + j;
      int slot = ((d >> 3) + (s >> 3)) & 15;
      o[j] = tile[s * 128 + slot * 8 + (d & 7)];
    }
    *(us8*)&vt[((size_t)hh * HD + d) * SEQ + sb + c8 * 8] = o;
  }
}

// ------------- kernel 6: flash attention, 32x32 MFMA, in-register softmax -------------
// grid (SEQ/128, NH); 4 waves x 32 q rows. KV tile 64, double-buffered LDS.
// swapped QK^T (mfma32(K,Q)): S^T col=q=lane&31, so softmax row is lane-local.
// P -> PV A-frag via cvt_pk_bf16 + v_permlane32_swap (no LDS round trip).
__global__ __launch_bounds__(256, 2) void k_attn(const unsigned short* __restrict__ qg,
    const unsigned short* __restrict__ kg, const unsigned short* __restrict__ vtg,
    float* __restrict__ outp) {
  const int h = blockIdx.y;
  const int qb0 = blockIdx.x * 128;
  const int t = threadIdx.x;
  const int w = t >> 6, l = t & 63;
  const int l31 = l & 31, hi = l >> 5;

  __shared__ unsigned short lK[2][64 * 128];  // [kv][d], 16B-chunk XOR-swizzled
  __shared__ unsigned short lV[2][128 * 64];  // [d][kv], 16B-chunk XOR-swizzled

  // Q B-frags: lane (l31,hi) holds Q[q=l31][d = ks*16 + hi*8 + j]
  bfv8 qf[8];
  {
    const unsigned short* qrow = qg + ((size_t)h * SEQ + qb0 + w * 32 + l31) * HD + hi * 8;
#pragma unroll
    for (int ks = 0; ks < 8; ++ks) qf[ks] = *(const bfv8*)(qrow + ks * 16);
  }

  f32x16 oacc[4];
#pragma unroll
  for (int dt = 0; dt < 4; ++dt)
#pragma unroll
    for (int r = 0; r < 16; ++r) oacc[dt][r] = 0.f;
  float m_run = -1e30f, l_run = 0.f;

#define STAGE_KV(b, tile)                                                              \
  do {                                                                                 \
    int kvbase = (tile) * 64;                                                          \
    _Pragma("unroll") for (int r = 0; r < 4; ++r) {                                    \
      int krow = w * 16 + r * 4 + (l >> 4);                                            \
      int ksrc = (l & 15) ^ (krow & 7);                                                \
      async16(&lK[b][(w * 16 + r * 4) * 128],                                          \
              kg + ((size_t)h * SEQ + kvbase + krow) * HD + ksrc * 8);                 \
      int vrow = w * 32 + r * 8 + (l >> 3);                                            \
      int vsrc = (l & 7) ^ (vrow & 7);                                                 \
      async16(&lV[b][(w * 32 + r * 8) * 64],                                           \
              vtg + ((size_t)h * HD + vrow) * SEQ + kvbase + vsrc * 8);                \
    }                                                                                  \
  } while (0)

  STAGE_KV(0, 0);
  int cur = 0;

  for (int tt = 0; tt < SEQ / 64; ++tt) {
    __syncthreads();          // drains prev staging (vmcnt 0) + protects buf reuse
    if (tt < SEQ / 64 - 1) STAGE_KV(cur ^ 1, tt + 1);

    // ---- S^T = K . Q^T : two 32x32 tiles over kv ----
    f32x16 st0, st1;
#pragma unroll
    for (int r = 0; r < 16; ++r) { st0[r] = 0.f; st1[r] = 0.f; }
#pragma unroll
    for (int ks = 0; ks < 8; ++ks) {
      int sw = l31 & 7;
      bfv8 kf0 = *(const bfv8*)&lK[cur][l31 * 128 + (((ks * 2 + hi) ^ sw)) * 8];
      bfv8 kf1 = *(const bfv8*)&lK[cur][(32 + l31) * 128 + (((ks * 2 + hi) ^ sw)) * 8];
      st0 = MFMA32(kf0, qf[ks], st0);
      st1 = MFMA32(kf1, qf[ks], st1);
    }

    // ---- online softmax in exp2 domain; lane owns q = l31 ----
    float pmax = st0[0];
#pragma unroll
    for (int r = 0; r < 16; ++r) {
      pmax = fmaxf(pmax, st0[r]);
      pmax = fmaxf(pmax, st1[r]);
    }
    pmax = fmaxf(pmax, __shfl_xor(pmax, 32));
    if (!__all(pmax <= m_run + 10.0f)) {        // defer-max: rescale only on growth
      float m_new = fmaxf(m_run, pmax);
      float alpha = exp2f(m_run - m_new);
#pragma unroll
      for (int r = 0; r < 16; ++r) {
        int qr = (r & 3) + 8 * (r >> 2) + 4 * hi;
        float ar = __shfl(alpha, qr);
#pragma unroll
        for (int dt = 0; dt < 4; ++dt) oacc[dt][r] *= ar;
      }
      l_run *= alpha;
      m_run = m_new;
    }
    float lsum = 0.f;
#pragma unroll
    for (int r = 0; r < 16; ++r) {
      st0[r] = exp2f(st0[r] - m_run);
      st1[r] = exp2f(st1[r] - m_run);
      lsum += st0[r] + st1[r];
    }
    lsum += __shfl_xor(lsum, 32);
    l_run += lsum;

    // ---- pack P into PV A-frags: cvt_pk + permlane32_swap ----
    // st reg r holds kv = (r&3) + 8*(r>>2) + 4*hi (within its 32-kv tile)
    bfv8 pa[4];
    {
      unsigned int a0 = cvtpk(st0[0], st0[1]), a1 = cvtpk(st0[2], st0[3]);
      unsigned int b0 = cvtpk(st0[4], st0[5]), b1 = cvtpk(st0[6], st0[7]);
      unsigned int c0 = cvtpk(st0[8], st0[9]), c1 = cvtpk(st0[10], st0[11]);
      unsigned int d0 = cvtpk(st0[12], st0[13]), d1 = cvtpk(st0[14], st0[15]);
      pl32swap(a0, b0); pl32swap(a1, b1); pl32swap(c0, d0); pl32swap(c1, d1);
      pa[0] = __builtin_bit_cast(bfv8, make_uint4(a0, a1, b0, b1));
      pa[1] = __builtin_bit_cast(bfv8, make_uint4(c0, c1, d0, d1));
      a0 = cvtpk(st1[0], st1[1]); a1 = cvtpk(st1[2], st1[3]);
      b0 = cvtpk(st1[4], st1[5]); b1 = cvtpk(st1[6], st1[7]);
      c0 = cvtpk(st1[8], st1[9]); c1 = cvtpk(st1[10], st1[11]);
      d0 = cvtpk(st1[12], st1[13]); d1 = cvtpk(st1[14], st1[15]);
      pl32swap(a0, b0); pl32swap(a1, b1); pl32swap(c0, d0); pl32swap(c1, d1);
      pa[2] = __builtin_bit_cast(bfv8, make_uint4(a0, a1, b0, b1));
      pa[3] = __builtin_bit_cast(bfv8, make_uint4(c0, c1, d0, d1));
    }

    // ---- O += P . V ----
#pragma unroll
    for (int dt = 0; dt < 4; ++dt) {
      int row = dt * 32 + l31;
      int sw = row & 7;
#pragma unroll
      for (int ksub = 0; ksub < 4; ++ksub) {
        bfv8 vf = *(const bfv8*)&lV[cur][row * 64 + (((ksub * 2 + hi) ^ sw)) * 8];
        oacc[dt] = MFMA32(pa[ksub], vf, oacc[dt]);
      }
    }
    cur ^= 1;
  }

  // ---- epilogue: O[q][d] / l[q]; oacc lane: d = dt*32+l31, q = (r&3)+8*(r>>2)+4*hi ----
  float linv = 1.0f / l_run;
#pragma unroll
  for (int r = 0; r < 16; ++r) {
    int qr = (r & 3) + 8 * (r >> 2) + 4 * hi;
    float lr = __shfl(linv, qr);
    float* orow = outp + (size_t)(qb0 + w * 32 + qr) * DIM + h * HD;
#pragma unroll
    for (int dt = 0; dt < 4; ++dt) orow[dt * 32 + l31] = oacc[dt][r] * lr;
  }
#undef STAGE_KV
}

extern "C" void kernel_launch(void* const* d_in, const int* in_sizes, int n_in,
                              void* d_out, int out_size, void* d_ws, size_t ws_size,
                              hipStream_t stream) {
  const float* hs = (const float*)d_in[0];
  const float* cosT = (const float*)d_in[1];
  const float* sinT = (const float*)d_in[2];
  const float* Wq = (const float*)d_in[3];
  const float* bq = (const float*)d_in[4];
  const float* Wk = (const float*)d_in[5];
  const float* bk = (const float*)d_in[6];
  const float* Wv = (const float*)d_in[7];
  const float* bv = (const float*)d_in[8];
  const float* gq = (const float*)d_in[9];
  const float* gk = (const float*)d_in[10];
  float* out = (float*)d_out;

  char* ws = (char*)d_ws;
  const size_t SZ_HS = (size_t)SEQ * DIM * 2;
  const size_t SZ_W = (size_t)DIM * DIM * 2;
  const size_t SZ_HEAD = (size_t)NH * SEQ * HD * 2;
  unsigned short* hsb = (unsigned short*)ws;               ws += SZ_HS;
  unsigned short* WqT = (unsigned short*)ws;               ws += SZ_W;
  unsigned short* WkT = (unsigned short*)ws;               ws += SZ_W;
  unsigned short* WvT = (unsigned short*)ws;               ws += SZ_W;
  unsigned short* q_b = (unsigned short*)ws;               ws += SZ_HEAD;
  unsigned short* k_b = (unsigned short*)ws;               ws += SZ_HEAD;
  unsigned short* v_b = (unsigned short*)ws;               ws += SZ_HEAD;
  unsigned short* vtr = (unsigned short*)ws;               ws += SZ_HEAD;

  int n4 = SEQ * DIM / 4;
  k_cast<<<dim3(n4 / 256), dim3(256), 0, stream>>>((const float4*)hs, (us4*)hsb, n4);
  k_transW<<<dim3(48, 48, 3), dim3(256), 0, stream>>>(Wq, Wk, Wv, WqT, WkT, WvT);
  k_gemm<<<dim3(24, 32, 3), dim3(256), 0, stream>>>(hsb, WqT, WkT, WvT, bq, bk, bv,
                                                    q_b, k_b, v_b);
  k_rmsrope<<<dim3(2 * NH * SEQ / 4), dim3(256), 0, stream>>>(q_b, k_b, cosT, sinT, gq, gk);
  k_transV<<<dim3(64, 24), dim3(256), 0, stream>>>(v_b, vtr);
  k_attn<<<dim3(32, 24), dim3(256), 0, stream>>>(q_b, k_b, vtr, out);
}